// Round 7
// baseline (1194.526 us; speedup 1.0000x reference)
//
#include <hip/hip_runtime.h>
#include <cstddef>

#define EPSF 1e-12f

constexpr int Bc = 16, Dc = 128, Lc = 4096, Kc = 4096;
constexpr int Nc = Bc * Lc;     // 65536
constexpr float TAU = 1e-4f;    // 2x split-bf16 err (~4e-5) + 8-bit pack err (~6e-5)
constexpr int RCAP = 32768;

typedef __attribute__((ext_vector_type(8))) short short8;
typedef __attribute__((ext_vector_type(4))) float f32x4;

__device__ __forceinline__ unsigned short f2bf(float f) {
    unsigned u = __float_as_uint(f);
    return (unsigned short)((u + 0x7fffu + ((u >> 16) & 1u)) >> 16);
}
__device__ __forceinline__ float bf2f(unsigned short u) {
    return __uint_as_float(((unsigned)u) << 16);
}

// ---------------------------------------------------------------------------
// Fused codebook prep: normalize -> cbn (f32) AND pack MFMA-operand blob.
// Blob layout: group g (16 codes) -> 8 frags (kd 0..3 x {hi,lo}) of 1024B;
// within a frag, 16B slot l = q*16 + (k&15) holds bf16 of dims (kd*4+q)*8..+7
// of code k. A wave reading blob + g*8192 + f*1024 + lane*16 gets its exact
// B-frag, lane-linear. Zero-inits loss / repair / done (graph-replay safe).
// ---------------------------------------------------------------------------
__global__ void k_prep(const float* __restrict__ emb, float* __restrict__ cbn,
                       char* __restrict__ blob, float* __restrict__ lacc,
                       int* __restrict__ rcnt, int* __restrict__ done) {
    __shared__ float cls[4][128];
    const int tid  = threadIdx.x;
    const int w    = tid >> 6;
    const int lane = tid & 63;
    const int k    = (blockIdx.x << 2) + w;

    float2 v = ((const float2*)(emb + (size_t)k * Dc))[lane];
    float s = v.x * v.x + v.y * v.y;
    #pragma unroll
    for (int off = 32; off > 0; off >>= 1) s += __shfl_down(s, off);
    s = __shfl(s, 0);
    float inv = 1.f / fmaxf(sqrtf(s), EPSF);
    v.x *= inv; v.y *= inv;
    ((float2*)(cbn + (size_t)k * Dc))[lane] = v;
    cls[w][lane * 2]     = v.x;
    cls[w][lane * 2 + 1] = v.y;
    if (blockIdx.x == 0 && tid == 0) { *lacc = 0.f; *rcnt = 0; *done = 0; }
    __syncthreads();

    if (tid < 64) {           // 4 codes x 16 chunks
        int kl = tid >> 4, c = tid & 15;
        int kk = (blockIdx.x << 2) + kl;
        int kd = c >> 2, q = c & 3;
        short8 hh, ll;
        #pragma unroll
        for (int j = 0; j < 8; ++j) {
            float f = cls[kl][c * 8 + j];
            unsigned short hb = f2bf(f);
            hh[j] = (short)hb;
            ll[j] = (short)f2bf(f - bf2f(hb));
        }
        size_t base = (size_t)(kk >> 4) * 8192 + (size_t)(q * 16 + (kk & 15)) * 16;
        *(short8*)(blob + base + (kd * 2 + 0) * 1024) = hh;
        *(short8*)(blob + base + (kd * 2 + 1) * 1024) = ll;
    }
}

// ---------------------------------------------------------------------------
// MFMA argmax, barrier-free K-loop. Block = 512 thr / 8 waves =
// (2 rowsets x 4 codesets), 128 rows/block, grid 512 -> 2 blocks/CU
// (16 waves/CU, 4 waves/SIMD: one wave's MFMA burst overlaps another's
// VALU fold burst — separate pipes, m114). 2MB blob is L2-resident: each
// wave reads its 8 B-frags per tile directly from global into VGPRs
// (no LDS staging, no K-loop barriers), ping-pong double-buffered via
// 2x-unroll. Per wave: 64 rows in A regs (rt=4, hi/lo split), 16
// codes/tile, 64 tiles of 64 codes. 8-bit packed fold (med3 second-best).
// Tail: LDS-transposed gather-write (no scattered 4B gathers).
// ---------------------------------------------------------------------------
__global__ __launch_bounds__(512, 4)
void k_argmax(const float* __restrict__ x, const char* __restrict__ blob,
              const float* __restrict__ cbn, float* __restrict__ invn,
              float* __restrict__ out, float* __restrict__ lossacc,
              int* __restrict__ rcnt, int* __restrict__ rlist) {
    __shared__ __align__(16) char smem[33280];
    float* xt   = (float*)smem;              // [64][129] (preamble overlay)
    float* invl = (float*)(smem + 33024);    // [64]

    const int tid  = threadIdx.x;
    const int w    = tid >> 6;
    const int lane = tid & 63;
    const int m16  = lane & 15;
    const int quad = lane >> 4;
    const int rs   = w >> 2;      // rowset 0/1 (64 rows each)
    const int cs   = w & 3;       // codeset 0..3 (16 codes per tile each)
    const int n0   = blockIdx.x * 128;
    const int bI   = n0 >> 12;
    const int l0   = n0 & (Lc - 1);
    const float* xb = x + (size_t)bI * Dc * Lc;

    // ---- preamble: 2 halves of 64 rows: transpose, normalize, build A frags
    short8 ah[4][4], al[4][4];
    for (int h = 0; h < 2; ++h) {
        __syncthreads();
        #pragma unroll
        for (int j = 0; j < 4; ++j) {
            int fl = tid + j * 512;              // 0..2047
            int d = fl >> 4, lq = fl & 15;
            float4 v = *(const float4*)(xb + (size_t)d * Lc + l0 + h * 64 + lq * 4);
            xt[(lq * 4 + 0) * 129 + d] = v.x;
            xt[(lq * 4 + 1) * 129 + d] = v.y;
            xt[(lq * 4 + 2) * 129 + d] = v.z;
            xt[(lq * 4 + 3) * 129 + d] = v.w;
        }
        __syncthreads();
        {   // row norms, 8 threads/row
            int row = tid >> 3, q = tid & 7;
            float s = 0.f;
            #pragma unroll
            for (int j = 0; j < 16; ++j) { float t = xt[row * 129 + q * 16 + j]; s += t * t; }
            s += __shfl_down(s, 1); s += __shfl_down(s, 2); s += __shfl_down(s, 4);
            if (q == 0) {
                float inv = 1.f / fmaxf(sqrtf(s), EPSF);
                invl[row] = inv;
                invn[n0 + h * 64 + row] = inv;
            }
        }
        __syncthreads();
        if (rs == h) {   // all 4 cs-waves of this rowset build the frags
            #pragma unroll
            for (int rt = 0; rt < 4; ++rt) {
                int rl = rt * 16 + m16;          // A layout: m = lane&15
                float inv = invl[rl];
                #pragma unroll
                for (int kd = 0; kd < 4; ++kd) {
                    int dof = kd * 32 + quad * 8;   // k = quad*8 + j
                    short8 hhv, llv;
                    #pragma unroll
                    for (int j = 0; j < 8; ++j) {
                        float xn = xt[rl * 129 + dof + j] * inv;
                        unsigned short hb = f2bf(xn);
                        hhv[j] = (short)hb;
                        llv[j] = (short)f2bf(xn - bf2f(hb));
                    }
                    ah[rt][kd] = hhv; al[rt][kd] = llv;
                }
            }
        }
    }
    __syncthreads();

    // ---- K loop: 64 tiles of 64 codes (16 per codeset), barrier-free ----
    const f32x4 fz = {0.f, 0.f, 0.f, 0.f};
    float Bb[16], Ss[16];
    #pragma unroll
    for (int i = 0; i < 16; ++i) { Bb[i] = -3.0e38f; Ss[i] = -3.0e38f; }
    unsigned kc8 = (unsigned)cs;     // packed tag = code>>4 = t*4+cs

    // wave's group for tile t lives at blob + t*32768 + cs*8192; frag f at
    // +f*1024 + lane*16 (f = kd*2 -> hi, kd*2+1 -> lo)
    const char* pb = blob + (size_t)cs * 8192 + (size_t)lane * 16;

    auto tileStep = [&](const short8* Bf) {
        f32x4 acc[4];
        #pragma unroll
        for (int kd = 0; kd < 4; ++kd) {
            short8 bh = Bf[kd * 2];
            short8 bl = Bf[kd * 2 + 1];
            #pragma unroll
            for (int rt = 0; rt < 4; ++rt)
                acc[rt] = __builtin_amdgcn_mfma_f32_16x16x32_bf16(
                    ah[rt][kd], bh, (kd == 0) ? fz : acc[rt], 0, 0, 0);
            #pragma unroll
            for (int rt = 0; rt < 4; ++rt)
                acc[rt] = __builtin_amdgcn_mfma_f32_16x16x32_bf16(
                    ah[rt][kd], bl, acc[rt], 0, 0, 0);
            #pragma unroll
            for (int rt = 0; rt < 4; ++rt)
                acc[rt] = __builtin_amdgcn_mfma_f32_16x16x32_bf16(
                    al[rt][kd], bh, acc[rt], 0, 0, 0);
        }
        // fold: 1 candidate per (slot,lane); 8-bit tag in low mantissa.
        // Since Ss <= Bb always, exact second-best update
        //   Ss = max(Ss, min(Bb, p))  ==  med3(Bb, p, Ss)  (1 instr).
        #pragma unroll
        for (int rt = 0; rt < 4; ++rt)
            #pragma unroll
            for (int rg = 0; rg < 4; ++rg) {
                int s = rt * 4 + rg;
                float p = __uint_as_float(
                    (__float_as_uint(acc[rt][rg]) & 0xFFFFFF00u) | kc8);
                Ss[s] = __builtin_amdgcn_fmed3f(Bb[s], p, Ss[s]);
                Bb[s] = fmaxf(Bb[s], p);
            }
        kc8 += 4;
    };

    short8 bA[8], bB[8];
    #pragma unroll
    for (int f = 0; f < 8; ++f) bA[f] = *(const short8*)(pb + f * 1024);

    for (int tt = 0; tt < 32; ++tt) {
        {   // even tile t = 2*tt: prefetch t+1 into bB, compute bA
            const int t = 2 * tt;
            const char* p = pb + (size_t)(t + 1) * 32768;
            #pragma unroll
            for (int f = 0; f < 8; ++f) bB[f] = *(const short8*)(p + f * 1024);
            tileStep(bA);
        }
        {   // odd tile t = 2*tt+1: prefetch t+1 into bA (clamp last), compute bB
            const int t = 2 * tt + 1;
            const size_t tn = (t < 63) ? (size_t)(t + 1) : (size_t)t;
            const char* p = pb + tn * 32768;
            #pragma unroll
            for (int f = 0; f < 8; ++f) bA[f] = *(const short8*)(p + f * 1024);
            tileStep(bB);
        }
    }

    // ---- epilogue: merge 16 m16-lanes per slot ----
    float mv1[16], mv2[16]; int mk1[16];
    #pragma unroll
    for (int s = 0; s < 16; ++s) {
        float v1 = Bb[s], v2 = Ss[s];
        int k1 = (int)(((__float_as_uint(v1) & 0xFFu) << 4) | (unsigned)m16);
        #pragma unroll
        for (int off = 1; off < 16; off <<= 1) {
            float ov1 = __shfl_xor(v1, off);
            float ov2 = __shfl_xor(v2, off);
            int   ok1 = __shfl_xor(k1, off);
            bool gt = ov1 > v1, eq = ov1 == v1;
            v2 = gt ? fmaxf(ov2, v1) : fmaxf(v2, ov1);
            v1 = gt ? ov1 : v1;
            k1 = gt ? ok1 : (eq ? min(k1, ok1) : k1);
        }
        mv1[s] = v1; mv2[s] = v2; mk1[s] = k1;
    }
    // cross-codeset merge via LDS: [128 rows][4 cs]
    float* Ev = (float*)smem;                // 2048 B
    float* Sv = (float*)(smem + 2048);
    int*   Kv = (int*)(smem + 4096);
    float* bsum = (float*)(smem + 6144);
    int*   sidx = (int*)(smem + 8192);       // [128] final code per row
    __syncthreads();
    if (tid == 0) *bsum = 0.f;
    if (m16 == 0) {
        #pragma unroll
        for (int s = 0; s < 16; ++s) {
            int rt = s >> 2, rg = s & 3;
            int row = rs * 64 + rt * 16 + quad * 4 + rg;   // C row = quad*4+reg
            Ev[row * 4 + cs] = mv1[s];
            Sv[row * 4 + cs] = mv2[s];
            Kv[row * 4 + cs] = mk1[s];
        }
    }
    __syncthreads();
    if (tid < 128) {
        float v1 = Ev[tid * 4], v2 = Sv[tid * 4];
        int   k1 = Kv[tid * 4];
        #pragma unroll
        for (int c = 1; c < 4; ++c) {
            float ov1 = Ev[tid * 4 + c], ov2 = Sv[tid * 4 + c];
            int   ok1 = Kv[tid * 4 + c];
            bool gt = ov1 > v1, eq = ov1 == v1;
            v2 = gt ? fmaxf(ov2, v1) : fmaxf(v2, ov1);
            v1 = gt ? ov1 : v1;
            k1 = gt ? ok1 : (eq ? min(k1, ok1) : k1);
        }
        sidx[tid] = k1;
        atomicAdd(bsum, v1);
        if (v1 - v2 < TAU) {
            int pos = atomicAdd(rcnt, 1);
            if (pos < RCAP) rlist[pos] = n0 + tid;
        }
    }
    __syncthreads();
    if (tid == 0) atomicAdd(lossacc, *bsum);

    // ---- fused output write via LDS transpose: 2 chunks of 64 rows.
    // Stage: thread t loads row (t>>3) of chunk (code myk), dims (t&7)*16..+15
    // -> coalesced 128B runs per row. Write: 64 lanes = 64 consecutive l,
    // fixed d -> contiguous 256B stores.
    int myk[2];
    #pragma unroll
    for (int c = 0; c < 2; ++c) myk[c] = sidx[c * 64 + (tid >> 3)];
    float* tb = (float*)smem;                // [64][130] = 33280 B
    float* ob = out + (size_t)bI * Dc * Lc + l0;
    #pragma unroll 1
    for (int c = 0; c < 2; ++c) {
        __syncthreads();                     // prior chunk reads / sidx done
        {
            const float4* src = (const float4*)(cbn + (size_t)myk[c] * Dc + (tid & 7) * 16);
            float4 v0 = src[0], v1 = src[1], v2 = src[2], v3 = src[3];
            float* dst = tb + (tid >> 3) * 130 + (tid & 7) * 16;
            *(float4*)(dst + 0)  = v0;
            *(float4*)(dst + 4)  = v1;
            *(float4*)(dst + 8)  = v2;
            *(float4*)(dst + 12) = v3;
        }
        __syncthreads();
        {
            int l = tid & 63, d0 = tid >> 6;     // wave = fixed d, l 0..63
            #pragma unroll
            for (int dd = 0; dd < 16; ++dd) {
                int d = d0 * 16 + dd;
                ob[(size_t)d * Lc + c * 64 + l] = tb[l * 130 + d];
            }
        }
    }
}

// ---------------------------------------------------------------------------
// Exact fp32 re-argmax for flagged queries; rewrites the output row with the
// exact code. Last block (device-scope done counter) writes the scalar loss.
// ---------------------------------------------------------------------------
__global__ __launch_bounds__(256)
void k_repair(const float* __restrict__ x, const float* __restrict__ invn,
              const float* __restrict__ cbn, float* __restrict__ out,
              const int* __restrict__ rcnt, const int* __restrict__ rlist,
              const float* __restrict__ lacc, int* __restrict__ done) {
    __shared__ float xs[128];
    __shared__ unsigned long long red[4];
    __shared__ int fk;
    int cnt = *rcnt; if (cnt > RCAP) cnt = RCAP;
    const int tid = threadIdx.x;
    for (int e = blockIdx.x; e < cnt; e += gridDim.x) {
        int n = rlist[e]; int b = n >> 12; int l = n & (Lc - 1);
        __syncthreads();
        if (tid < 128)
            xs[tid] = x[(size_t)b * Dc * Lc + (size_t)tid * Lc + l] * invn[n];
        __syncthreads();
        const float4* xv = (const float4*)xs;
        float best = -3.0e38f; int bk = 0;
        #pragma unroll 1
        for (int i = 0; i < 16; ++i) {
            int k = i * 256 + tid;                // ascending: '>' keeps min k
            const float4* cr = (const float4*)(cbn + (size_t)k * Dc);
            float s = 0.f;
            #pragma unroll
            for (int j = 0; j < 32; ++j) {
                float4 c = cr[j], xx = xv[j];
                s = fmaf(c.x, xx.x, s); s = fmaf(c.y, xx.y, s);
                s = fmaf(c.z, xx.z, s); s = fmaf(c.w, xx.w, s);
            }
            if (s > best) { best = s; bk = k; }
        }
        unsigned kb = __float_as_uint(best);
        kb = (kb & 0x80000000u) ? ~kb : (kb | 0x80000000u);
        unsigned long long pk =
            ((unsigned long long)kb << 32) | (unsigned)(0xFFFFFFFFu - (unsigned)bk);
        #pragma unroll
        for (int off = 32; off >= 1; off >>= 1) {
            unsigned long long o = __shfl_xor(pk, off);
            pk = (o > pk) ? o : pk;
        }
        if ((tid & 63) == 0) red[tid >> 6] = pk;
        __syncthreads();
        if (tid == 0) {
            unsigned long long m = red[0];
            for (int i = 1; i < 4; ++i) if (red[i] > m) m = red[i];
            fk = (int)(0xFFFFFFFFu - (unsigned)(m & 0xFFFFFFFFull));
        }
        __syncthreads();
        if (tid < 128)       // rewrite output row with exact code
            out[(size_t)b * Dc * Lc + (size_t)tid * Lc + l] = cbn[(size_t)fk * Dc + tid];
    }
    // ---- fused loss finalize: last block writes the scalar
    __syncthreads();
    if (tid == 0) {
        int old = atomicAdd(done, 1);
        if (old == (int)gridDim.x - 1)
            out[(size_t)Bc * Dc * Lc] = 2.0f - 2.0f * (*lacc) / (float)Nc;
    }
}

// ---------------------------------------------------------------------------
extern "C" void kernel_launch(void* const* d_in, const int* in_sizes, int n_in,
                              void* d_out, int out_size, void* d_ws, size_t ws_size,
                              hipStream_t stream) {
    const float* x   = (const float*)d_in[0];   // [16][128][4096] fp32
    const float* emb = (const float*)d_in[1];   // [4096][128] fp32
    float* out = (float*)d_out;

    char* ws = (char*)d_ws;
    float* cbn  = (float*)ws;                                  // 2 MB
    char*  blob = ws + (2u << 20);                             // 2 MB
    float* invn = (float*)(ws + (4u << 20));                   // 256 KB
    char*  b5   = ws + (4u << 20) + (512u << 10);
    float* lacc = (float*)b5;
    int*   rcnt = (int*)(b5 + 64);
    int*   done = (int*)(b5 + 128);
    int*   rlist= (int*)(b5 + 1024);                           // 128 KB

    k_prep  <<<Kc / 4,   256, 0, stream>>>(emb, cbn, blob, lacc, rcnt, done);
    k_argmax<<<Nc / 128, 512, 0, stream>>>(x, blob, cbn, invn, out, lacc, rcnt, rlist);
    k_repair<<<1024,     256, 0, stream>>>(x, invn, cbn, out, rcnt, rlist, lacc, done);
}

// Round 8
// 364.572 us; speedup vs baseline: 3.2765x; 3.2765x over previous
//
#include <hip/hip_runtime.h>
#include <cstddef>

#define EPSF 1e-12f

constexpr int Bc = 16, Dc = 128, Lc = 4096, Kc = 4096;
constexpr int Nc = Bc * Lc;     // 65536
constexpr float TAU = 1e-4f;    // 2x split-bf16 err (~4e-5) + 8-bit pack err (~6e-5)
constexpr int RCAP = 32768;

typedef __attribute__((ext_vector_type(8))) short short8;
typedef __attribute__((ext_vector_type(4))) float f32x4;

__device__ __forceinline__ unsigned short f2bf(float f) {
    unsigned u = __float_as_uint(f);
    return (unsigned short)((u + 0x7fffu + ((u >> 16) & 1u)) >> 16);
}
__device__ __forceinline__ float bf2f(unsigned short u) {
    return __uint_as_float(((unsigned)u) << 16);
}

// ---------------------------------------------------------------------------
// Fused codebook prep: normalize -> cbn (f32) AND pack MFMA-operand blob.
// Blob layout: group g (16 codes) -> 8 frags (kd 0..3 x {hi,lo}) of 1024B;
// within a frag, 16B slot l = q*16 + (k&15) holds bf16 of dims (kd*4+q)*8..+7
// of code k. A wave reading blob + g*8192 + f*1024 + lane*16 gets its exact
// B-frag, lane-linear. Zero-inits loss / repair / done (graph-replay safe).
// ---------------------------------------------------------------------------
__global__ void k_prep(const float* __restrict__ emb, float* __restrict__ cbn,
                       char* __restrict__ blob, float* __restrict__ lacc,
                       int* __restrict__ rcnt, int* __restrict__ done) {
    __shared__ float cls[4][128];
    const int tid  = threadIdx.x;
    const int w    = tid >> 6;
    const int lane = tid & 63;
    const int k    = (blockIdx.x << 2) + w;

    float2 v = ((const float2*)(emb + (size_t)k * Dc))[lane];
    float s = v.x * v.x + v.y * v.y;
    #pragma unroll
    for (int off = 32; off > 0; off >>= 1) s += __shfl_down(s, off);
    s = __shfl(s, 0);
    float inv = 1.f / fmaxf(sqrtf(s), EPSF);
    v.x *= inv; v.y *= inv;
    ((float2*)(cbn + (size_t)k * Dc))[lane] = v;
    cls[w][lane * 2]     = v.x;
    cls[w][lane * 2 + 1] = v.y;
    if (blockIdx.x == 0 && tid == 0) { *lacc = 0.f; *rcnt = 0; *done = 0; }
    __syncthreads();

    if (tid < 64) {           // 4 codes x 16 chunks
        int kl = tid >> 4, c = tid & 15;
        int kk = (blockIdx.x << 2) + kl;
        int kd = c >> 2, q = c & 3;
        short8 hh, ll;
        #pragma unroll
        for (int j = 0; j < 8; ++j) {
            float f = cls[kl][c * 8 + j];
            unsigned short hb = f2bf(f);
            hh[j] = (short)hb;
            ll[j] = (short)f2bf(f - bf2f(hb));
        }
        size_t base = (size_t)(kk >> 4) * 8192 + (size_t)(q * 16 + (kk & 15)) * 16;
        *(short8*)(blob + base + (kd * 2 + 0) * 1024) = hh;
        *(short8*)(blob + base + (kd * 2 + 1) * 1024) = ll;
    }
}

// ---------------------------------------------------------------------------
// MFMA argmax, barrier-free software-pipelined K-loop. Block = 512 thr /
// 8 waves = (4 rowsets x 2 codesets), 256 rows/block, grid 256. 2MB blob is
// L2-resident; each wave streams its B-frags directly global->VGPR.
// Pipeline (per kd-group): 12 MFMAs of tile t -> 2-frag refill for t+1 ->
// fold 4 slots of tile t-1 (acc ping-pong accA/accB). Fold and refill issue
// into the MFMA pipe's throughput gaps instead of serializing after a
// 48-MFMA burst. Rolling 8-frag B buffer (not 16) funds the second acc set:
// ~240 regs/wave, 2 waves/SIMD. Numerics identical to the round-6 kernel.
// Tail: LDS-transposed gather-write.
// ---------------------------------------------------------------------------
__global__ __launch_bounds__(512, 2)
void k_argmax(const float* __restrict__ x, const char* __restrict__ blob,
              const float* __restrict__ cbn, float* __restrict__ invn,
              float* __restrict__ out, float* __restrict__ lossacc,
              int* __restrict__ rcnt, int* __restrict__ rlist) {
    __shared__ __align__(16) char smem[33280];
    float* xt   = (float*)smem;              // [64][129] (preamble overlay)
    float* invl = (float*)(smem + 33024);    // [64]

    const int tid  = threadIdx.x;
    const int w    = tid >> 6;
    const int lane = tid & 63;
    const int m16  = lane & 15;
    const int quad = lane >> 4;
    const int rs   = w >> 1;      // rowset 0..3 (64 rows each)
    const int cs   = w & 1;       // codeset 0/1 (16 codes per tile)
    const int n0   = blockIdx.x * 256;
    const int bI   = n0 >> 12;
    const int l0   = n0 & (Lc - 1);
    const float* xb = x + (size_t)bI * Dc * Lc;

    // ---- preamble: 4 halves of 64 rows: transpose, normalize, build A frags
    short8 ah[4][4], al[4][4];
    for (int h = 0; h < 4; ++h) {
        __syncthreads();
        #pragma unroll
        for (int j = 0; j < 4; ++j) {
            int fl = tid + j * 512;              // 0..2047
            int d = fl >> 4, lq = fl & 15;
            float4 v = *(const float4*)(xb + (size_t)d * Lc + l0 + h * 64 + lq * 4);
            xt[(lq * 4 + 0) * 129 + d] = v.x;
            xt[(lq * 4 + 1) * 129 + d] = v.y;
            xt[(lq * 4 + 2) * 129 + d] = v.z;
            xt[(lq * 4 + 3) * 129 + d] = v.w;
        }
        __syncthreads();
        {   // row norms, 8 threads/row
            int row = tid >> 3, q = tid & 7;
            float s = 0.f;
            #pragma unroll
            for (int j = 0; j < 16; ++j) { float t = xt[row * 129 + q * 16 + j]; s += t * t; }
            s += __shfl_down(s, 1); s += __shfl_down(s, 2); s += __shfl_down(s, 4);
            if (q == 0) {
                float inv = 1.f / fmaxf(sqrtf(s), EPSF);
                invl[row] = inv;
                invn[n0 + h * 64 + row] = inv;
            }
        }
        __syncthreads();
        if (rs == h) {   // both cs-waves of this rowset build the frags
            #pragma unroll
            for (int rt = 0; rt < 4; ++rt) {
                int rl = rt * 16 + m16;          // A layout: m = lane&15
                float inv = invl[rl];
                #pragma unroll
                for (int kd = 0; kd < 4; ++kd) {
                    int dof = kd * 32 + quad * 8;   // k = quad*8 + j
                    short8 hhv, llv;
                    #pragma unroll
                    for (int j = 0; j < 8; ++j) {
                        float xn = xt[rl * 129 + dof + j] * inv;
                        unsigned short hb = f2bf(xn);
                        hhv[j] = (short)hb;
                        llv[j] = (short)f2bf(xn - bf2f(hb));
                    }
                    ah[rt][kd] = hhv; al[rt][kd] = llv;
                }
            }
        }
    }
    __syncthreads();

    // ---- K loop: 128 tiles of 32 codes (16 per codeset), pipelined ----
    const f32x4 fz = {0.f, 0.f, 0.f, 0.f};
    float Bb[16], Ss[16];
    #pragma unroll
    for (int i = 0; i < 16; ++i) { Bb[i] = -3.0e38f; Ss[i] = -3.0e38f; }

    // wave's group for tile t: blob + t*16384 + cs*8192; frag f at
    // +f*1024 + lane*16 (f = kd*2 -> hi, kd*2+1 -> lo)
    const char* pb = blob + (size_t)cs * 8192 + (size_t)lane * 16;

    short8 bf[8];
    f32x4 accA[4], accB[4];

    // 12 MFMAs of one kd-group (order per acc: hh, hl, lh — identical chain)
    auto mfmaKd = [&](f32x4* acc, const short8* b2, int kd) {
        short8 bh = b2[0], bl = b2[1];
        #pragma unroll
        for (int rt = 0; rt < 4; ++rt)
            acc[rt] = __builtin_amdgcn_mfma_f32_16x16x32_bf16(
                ah[rt][kd], bh, (kd == 0) ? fz : acc[rt], 0, 0, 0);
        #pragma unroll
        for (int rt = 0; rt < 4; ++rt)
            acc[rt] = __builtin_amdgcn_mfma_f32_16x16x32_bf16(
                ah[rt][kd], bl, acc[rt], 0, 0, 0);
        #pragma unroll
        for (int rt = 0; rt < 4; ++rt)
            acc[rt] = __builtin_amdgcn_mfma_f32_16x16x32_bf16(
                al[rt][kd], bh, acc[rt], 0, 0, 0);
    };
    // fold 4 slots (rt == kd) of a completed acc; Ss<=Bb invariant makes
    // med3(Bb, p, Ss) the exact second-best update.
    auto foldKd = [&](const f32x4& a4, int kd, unsigned tag) {
        #pragma unroll
        for (int rg = 0; rg < 4; ++rg) {
            int s = kd * 4 + rg;
            float p = __uint_as_float(
                (__float_as_uint(a4[rg]) & 0xFFFFFF00u) | tag);
            Ss[s] = __builtin_amdgcn_fmed3f(Bb[s], p, Ss[s]);
            Bb[s] = fmaxf(Bb[s], p);
        }
    };
    auto refill = [&](const char* pn, int kd) {
        bf[2 * kd]     = *(const short8*)(pn + (2 * kd) * 1024);
        bf[2 * kd + 1] = *(const short8*)(pn + (2 * kd + 1) * 1024);
    };

    #pragma unroll
    for (int f = 0; f < 8; ++f) bf[f] = *(const short8*)(pb + f * 1024);

    {   // tile 0 -> accA, refill <- tile 1 (no fold yet)
        const char* pn = pb + 16384;
        #pragma unroll
        for (int kd = 0; kd < 4; ++kd) { mfmaKd(accA, &bf[2 * kd], kd); refill(pn, kd); }
    }
    for (int tt = 0; tt < 63; ++tt) {
        {   // tile 2tt+1 -> accB; fold accA (tile 2tt); refill <- tile 2tt+2
            const char* pn = pb + (size_t)(2 * tt + 2) * 16384;
            unsigned tg = (unsigned)(4 * tt) + (unsigned)cs;
            #pragma unroll
            for (int kd = 0; kd < 4; ++kd) {
                mfmaKd(accB, &bf[2 * kd], kd);
                refill(pn, kd);
                foldKd(accA[kd], kd, tg);
            }
        }
        {   // tile 2tt+2 -> accA; fold accB (tile 2tt+1); refill <- tile 2tt+3
            const char* pn = pb + (size_t)(2 * tt + 3) * 16384;
            unsigned tg = (unsigned)(4 * tt + 2) + (unsigned)cs;
            #pragma unroll
            for (int kd = 0; kd < 4; ++kd) {
                mfmaKd(accA, &bf[2 * kd], kd);
                refill(pn, kd);
                foldKd(accB[kd], kd, tg);
            }
        }
    }
    {   // tile 127 -> accB; fold accA (tile 126)
        unsigned tg = 252u + (unsigned)cs;
        #pragma unroll
        for (int kd = 0; kd < 4; ++kd) { mfmaKd(accB, &bf[2 * kd], kd); foldKd(accA[kd], kd, tg); }
    }
    {   // fold accB (tile 127)
        unsigned tg = 254u + (unsigned)cs;
        #pragma unroll
        for (int kd = 0; kd < 4; ++kd) foldKd(accB[kd], kd, tg);
    }

    // ---- epilogue: merge 16 m16-lanes per slot ----
    float mv1[16], mv2[16]; int mk1[16];
    #pragma unroll
    for (int s = 0; s < 16; ++s) {
        float v1 = Bb[s], v2 = Ss[s];
        int k1 = (int)(((__float_as_uint(v1) & 0xFFu) << 4) | (unsigned)m16);
        #pragma unroll
        for (int off = 1; off < 16; off <<= 1) {
            float ov1 = __shfl_xor(v1, off);
            float ov2 = __shfl_xor(v2, off);
            int   ok1 = __shfl_xor(k1, off);
            bool gt = ov1 > v1, eq = ov1 == v1;
            v2 = gt ? fmaxf(ov2, v1) : fmaxf(v2, ov1);
            v1 = gt ? ov1 : v1;
            k1 = gt ? ok1 : (eq ? min(k1, ok1) : k1);
        }
        mv1[s] = v1; mv2[s] = v2; mk1[s] = k1;
    }
    // cross-codeset merge via LDS: [256 rows][2 cs]
    float* Ev = (float*)smem;                // 2048 B
    float* Sv = (float*)(smem + 2048);
    int*   Kv = (int*)(smem + 4096);
    float* bsum = (float*)(smem + 6144);
    int*   sidx = (int*)(smem + 8192);       // [256] final code per row
    __syncthreads();
    if (tid == 0) *bsum = 0.f;
    if (m16 == 0) {
        #pragma unroll
        for (int s = 0; s < 16; ++s) {
            int rt = s >> 2, rg = s & 3;
            int row = rs * 64 + rt * 16 + quad * 4 + rg;   // C row = quad*4+reg
            Ev[row * 2 + cs] = mv1[s];
            Sv[row * 2 + cs] = mv2[s];
            Kv[row * 2 + cs] = mk1[s];
        }
    }
    __syncthreads();
    if (tid < 256) {
        float v1 = Ev[tid * 2], v2 = Sv[tid * 2];
        int   k1 = Kv[tid * 2];
        float ov1 = Ev[tid * 2 + 1], ov2 = Sv[tid * 2 + 1];
        int   ok1 = Kv[tid * 2 + 1];
        bool gt = ov1 > v1, eq = ov1 == v1;
        v2 = gt ? fmaxf(ov2, v1) : fmaxf(v2, ov1);
        v1 = gt ? ov1 : v1;
        k1 = gt ? ok1 : (eq ? min(k1, ok1) : k1);
        sidx[tid] = k1;
        atomicAdd(bsum, v1);
        if (v1 - v2 < TAU) {
            int pos = atomicAdd(rcnt, 1);
            if (pos < RCAP) rlist[pos] = n0 + tid;
        }
    }
    __syncthreads();
    if (tid == 0) atomicAdd(lossacc, *bsum);

    // ---- fused output write via LDS transpose: 4 chunks of 64 rows.
    int myk[4];
    #pragma unroll
    for (int c = 0; c < 4; ++c) myk[c] = sidx[c * 64 + (tid >> 3)];
    float* tb = (float*)smem;                // [64][130] = 33280 B
    float* ob = out + (size_t)bI * Dc * Lc + l0;
    #pragma unroll 1
    for (int c = 0; c < 4; ++c) {
        __syncthreads();                     // prior chunk reads / sidx done
        {
            const float4* src = (const float4*)(cbn + (size_t)myk[c] * Dc + (tid & 7) * 16);
            float4 v0 = src[0], v1 = src[1], v2 = src[2], v3 = src[3];
            float* dst = tb + (tid >> 3) * 130 + (tid & 7) * 16;
            *(float4*)(dst + 0)  = v0;
            *(float4*)(dst + 4)  = v1;
            *(float4*)(dst + 8)  = v2;
            *(float4*)(dst + 12) = v3;
        }
        __syncthreads();
        {
            int l = tid & 63, d0 = tid >> 6;     // wave = fixed d, l 0..63
            #pragma unroll
            for (int dd = 0; dd < 16; ++dd) {
                int d = d0 * 16 + dd;
                ob[(size_t)d * Lc + c * 64 + l] = tb[l * 130 + d];
            }
        }
    }
}

// ---------------------------------------------------------------------------
// Exact fp32 re-argmax for flagged queries; rewrites the output row with the
// exact code. Last block (device-scope done counter) writes the scalar loss.
// ---------------------------------------------------------------------------
__global__ __launch_bounds__(256)
void k_repair(const float* __restrict__ x, const float* __restrict__ invn,
              const float* __restrict__ cbn, float* __restrict__ out,
              const int* __restrict__ rcnt, const int* __restrict__ rlist,
              const float* __restrict__ lacc, int* __restrict__ done) {
    __shared__ float xs[128];
    __shared__ unsigned long long red[4];
    __shared__ int fk;
    int cnt = *rcnt; if (cnt > RCAP) cnt = RCAP;
    const int tid = threadIdx.x;
    for (int e = blockIdx.x; e < cnt; e += gridDim.x) {
        int n = rlist[e]; int b = n >> 12; int l = n & (Lc - 1);
        __syncthreads();
        if (tid < 128)
            xs[tid] = x[(size_t)b * Dc * Lc + (size_t)tid * Lc + l] * invn[n];
        __syncthreads();
        const float4* xv = (const float4*)xs;
        float best = -3.0e38f; int bk = 0;
        #pragma unroll 1
        for (int i = 0; i < 16; ++i) {
            int k = i * 256 + tid;                // ascending: '>' keeps min k
            const float4* cr = (const float4*)(cbn + (size_t)k * Dc);
            float s = 0.f;
            #pragma unroll
            for (int j = 0; j < 32; ++j) {
                float4 c = cr[j], xx = xv[j];
                s = fmaf(c.x, xx.x, s); s = fmaf(c.y, xx.y, s);
                s = fmaf(c.z, xx.z, s); s = fmaf(c.w, xx.w, s);
            }
            if (s > best) { best = s; bk = k; }
        }
        unsigned kb = __float_as_uint(best);
        kb = (kb & 0x80000000u) ? ~kb : (kb | 0x80000000u);
        unsigned long long pk =
            ((unsigned long long)kb << 32) | (unsigned)(0xFFFFFFFFu - (unsigned)bk);
        #pragma unroll
        for (int off = 32; off >= 1; off >>= 1) {
            unsigned long long o = __shfl_xor(pk, off);
            pk = (o > pk) ? o : pk;
        }
        if ((tid & 63) == 0) red[tid >> 6] = pk;
        __syncthreads();
        if (tid == 0) {
            unsigned long long m = red[0];
            for (int i = 1; i < 4; ++i) if (red[i] > m) m = red[i];
            fk = (int)(0xFFFFFFFFu - (unsigned)(m & 0xFFFFFFFFull));
        }
        __syncthreads();
        if (tid < 128)       // rewrite output row with exact code
            out[(size_t)b * Dc * Lc + (size_t)tid * Lc + l] = cbn[(size_t)fk * Dc + tid];
    }
    // ---- fused loss finalize: last block writes the scalar
    __syncthreads();
    if (tid == 0) {
        int old = atomicAdd(done, 1);
        if (old == (int)gridDim.x - 1)
            out[(size_t)Bc * Dc * Lc] = 2.0f - 2.0f * (*lacc) / (float)Nc;
    }
}

// ---------------------------------------------------------------------------
extern "C" void kernel_launch(void* const* d_in, const int* in_sizes, int n_in,
                              void* d_out, int out_size, void* d_ws, size_t ws_size,
                              hipStream_t stream) {
    const float* x   = (const float*)d_in[0];   // [16][128][4096] fp32
    const float* emb = (const float*)d_in[1];   // [4096][128] fp32
    float* out = (float*)d_out;

    char* ws = (char*)d_ws;
    float* cbn  = (float*)ws;                                  // 2 MB
    char*  blob = ws + (2u << 20);                             // 2 MB
    float* invn = (float*)(ws + (4u << 20));                   // 256 KB
    char*  b5   = ws + (4u << 20) + (512u << 10);
    float* lacc = (float*)b5;
    int*   rcnt = (int*)(b5 + 64);
    int*   done = (int*)(b5 + 128);
    int*   rlist= (int*)(b5 + 1024);                           // 128 KB

    k_prep  <<<Kc / 4,   256, 0, stream>>>(emb, cbn, blob, lacc, rcnt, done);
    k_argmax<<<Nc / 256, 512, 0, stream>>>(x, blob, cbn, invn, out, lacc, rcnt, rlist);
    k_repair<<<1024,     256, 0, stream>>>(x, invn, cbn, out, rcnt, rlist, lacc, done);
}

// Round 9
// 364.039 us; speedup vs baseline: 3.2813x; 1.0015x over previous
//
#include <hip/hip_runtime.h>
#include <cstddef>

#define EPSF 1e-12f

constexpr int Bc = 16, Dc = 128, Lc = 4096, Kc = 4096;
constexpr int Nc = Bc * Lc;     // 65536
constexpr float TAU = 1e-4f;    // 2x split-bf16 err (~4e-5) + 8-bit pack err (~6e-5)
constexpr int RCAP = 32768;

typedef __attribute__((ext_vector_type(8))) short short8;
typedef __attribute__((ext_vector_type(4))) float f32x4;

__device__ __forceinline__ unsigned short f2bf(float f) {
    unsigned u = __float_as_uint(f);
    return (unsigned short)((u + 0x7fffu + ((u >> 16) & 1u)) >> 16);
}
__device__ __forceinline__ float bf2f(unsigned short u) {
    return __uint_as_float(((unsigned)u) << 16);
}

// ---------------------------------------------------------------------------
// Fused codebook prep: normalize -> cbn (f32) AND pack MFMA-operand blob.
// Blob layout: group g (16 codes) -> 8 frags (kd 0..3 x {hi,lo}) of 1024B;
// within a frag, 16B slot l = q*16 + (k&15) holds bf16 of dims (kd*4+q)*8..+7
// of code k. A wave reading blob + g*8192 + f*1024 + lane*16 gets its exact
// B-frag, lane-linear. Zero-inits loss / repair / done (graph-replay safe).
// ---------------------------------------------------------------------------
__global__ void k_prep(const float* __restrict__ emb, float* __restrict__ cbn,
                       char* __restrict__ blob, float* __restrict__ lacc,
                       int* __restrict__ rcnt, int* __restrict__ done) {
    __shared__ float cls[4][128];
    const int tid  = threadIdx.x;
    const int w    = tid >> 6;
    const int lane = tid & 63;
    const int k    = (blockIdx.x << 2) + w;

    float2 v = ((const float2*)(emb + (size_t)k * Dc))[lane];
    float s = v.x * v.x + v.y * v.y;
    #pragma unroll
    for (int off = 32; off > 0; off >>= 1) s += __shfl_down(s, off);
    s = __shfl(s, 0);
    float inv = 1.f / fmaxf(sqrtf(s), EPSF);
    v.x *= inv; v.y *= inv;
    ((float2*)(cbn + (size_t)k * Dc))[lane] = v;
    cls[w][lane * 2]     = v.x;
    cls[w][lane * 2 + 1] = v.y;
    if (blockIdx.x == 0 && tid == 0) { *lacc = 0.f; *rcnt = 0; *done = 0; }
    __syncthreads();

    if (tid < 64) {           // 4 codes x 16 chunks
        int kl = tid >> 4, c = tid & 15;
        int kk = (blockIdx.x << 2) + kl;
        int kd = c >> 2, q = c & 3;
        short8 hh, ll;
        #pragma unroll
        for (int j = 0; j < 8; ++j) {
            float f = cls[kl][c * 8 + j];
            unsigned short hb = f2bf(f);
            hh[j] = (short)hb;
            ll[j] = (short)f2bf(f - bf2f(hb));
        }
        size_t base = (size_t)(kk >> 4) * 8192 + (size_t)(q * 16 + (kk & 15)) * 16;
        *(short8*)(blob + base + (kd * 2 + 0) * 1024) = hh;
        *(short8*)(blob + base + (kd * 2 + 1) * 1024) = ll;
    }
}

// ---------------------------------------------------------------------------
// MFMA argmax, barrier-free K-loop (round-6 structure: best measured,
// 190 us). Block = 512 thr / 8 waves = (4 rowsets x 2 codesets), 256
// rows/block, grid 256. 2MB blob is L2-resident: each wave reads its 8
// B-frags per tile directly global->VGPR (no LDS staging, no K-loop
// barriers), ping-pong double-buffered via 2x-unroll. Per wave: 64 rows in
// A regs (rt=4, hi/lo split), 16 codes/tile, 128 tiles. 8-bit packed fold;
// med3 second-best (exact under Ss<=Bb invariant). setprio(1) around the
// MFMA cluster: barrier-free waves drift out of phase, so priority keeps
// the matrix pipe fed while other waves fold.
// Tail: LDS-transposed gather-write (no scattered 4B gathers).
// ---------------------------------------------------------------------------
__global__ __launch_bounds__(512, 2)
void k_argmax(const float* __restrict__ x, const char* __restrict__ blob,
              const float* __restrict__ cbn, float* __restrict__ invn,
              float* __restrict__ out, float* __restrict__ lossacc,
              int* __restrict__ rcnt, int* __restrict__ rlist) {
    __shared__ __align__(16) char smem[33280];
    float* xt   = (float*)smem;              // [64][129] (preamble overlay)
    float* invl = (float*)(smem + 33024);    // [64]

    const int tid  = threadIdx.x;
    const int w    = tid >> 6;
    const int lane = tid & 63;
    const int m16  = lane & 15;
    const int quad = lane >> 4;
    const int rs   = w >> 1;      // rowset 0..3 (64 rows each)
    const int cs   = w & 1;       // codeset 0/1 (16 codes per tile)
    const int n0   = blockIdx.x * 256;
    const int bI   = n0 >> 12;
    const int l0   = n0 & (Lc - 1);
    const float* xb = x + (size_t)bI * Dc * Lc;

    // ---- preamble: 4 halves of 64 rows: transpose, normalize, build A frags
    short8 ah[4][4], al[4][4];
    for (int h = 0; h < 4; ++h) {
        __syncthreads();
        #pragma unroll
        for (int j = 0; j < 4; ++j) {
            int fl = tid + j * 512;              // 0..2047
            int d = fl >> 4, lq = fl & 15;
            float4 v = *(const float4*)(xb + (size_t)d * Lc + l0 + h * 64 + lq * 4);
            xt[(lq * 4 + 0) * 129 + d] = v.x;
            xt[(lq * 4 + 1) * 129 + d] = v.y;
            xt[(lq * 4 + 2) * 129 + d] = v.z;
            xt[(lq * 4 + 3) * 129 + d] = v.w;
        }
        __syncthreads();
        {   // row norms, 8 threads/row
            int row = tid >> 3, q = tid & 7;
            float s = 0.f;
            #pragma unroll
            for (int j = 0; j < 16; ++j) { float t = xt[row * 129 + q * 16 + j]; s += t * t; }
            s += __shfl_down(s, 1); s += __shfl_down(s, 2); s += __shfl_down(s, 4);
            if (q == 0) {
                float inv = 1.f / fmaxf(sqrtf(s), EPSF);
                invl[row] = inv;
                invn[n0 + h * 64 + row] = inv;
            }
        }
        __syncthreads();
        if (rs == h) {   // both cs-waves of this rowset build the frags
            #pragma unroll
            for (int rt = 0; rt < 4; ++rt) {
                int rl = rt * 16 + m16;          // A layout: m = lane&15
                float inv = invl[rl];
                #pragma unroll
                for (int kd = 0; kd < 4; ++kd) {
                    int dof = kd * 32 + quad * 8;   // k = quad*8 + j
                    short8 hhv, llv;
                    #pragma unroll
                    for (int j = 0; j < 8; ++j) {
                        float xn = xt[rl * 129 + dof + j] * inv;
                        unsigned short hb = f2bf(xn);
                        hhv[j] = (short)hb;
                        llv[j] = (short)f2bf(xn - bf2f(hb));
                    }
                    ah[rt][kd] = hhv; al[rt][kd] = llv;
                }
            }
        }
    }
    __syncthreads();

    // ---- K loop: 128 tiles of 32 codes (16 per codeset), barrier-free ----
    const f32x4 fz = {0.f, 0.f, 0.f, 0.f};
    float Bb[16], Ss[16];
    #pragma unroll
    for (int i = 0; i < 16; ++i) { Bb[i] = -3.0e38f; Ss[i] = -3.0e38f; }
    unsigned kc8 = (unsigned)cs;     // packed tag = code>>4 = t*2+cs

    const char* pb = blob + (size_t)cs * 8192 + (size_t)lane * 16;

    auto tileStep = [&](const short8* Bf) {
        f32x4 acc[4];
        __builtin_amdgcn_s_setprio(1);
        #pragma unroll
        for (int kd = 0; kd < 4; ++kd) {
            short8 bh = Bf[kd * 2];
            short8 bl = Bf[kd * 2 + 1];
            #pragma unroll
            for (int rt = 0; rt < 4; ++rt)
                acc[rt] = __builtin_amdgcn_mfma_f32_16x16x32_bf16(
                    ah[rt][kd], bh, (kd == 0) ? fz : acc[rt], 0, 0, 0);
            #pragma unroll
            for (int rt = 0; rt < 4; ++rt)
                acc[rt] = __builtin_amdgcn_mfma_f32_16x16x32_bf16(
                    ah[rt][kd], bl, acc[rt], 0, 0, 0);
            #pragma unroll
            for (int rt = 0; rt < 4; ++rt)
                acc[rt] = __builtin_amdgcn_mfma_f32_16x16x32_bf16(
                    al[rt][kd], bh, acc[rt], 0, 0, 0);
        }
        __builtin_amdgcn_s_setprio(0);
        // fold: 1 candidate per (slot,lane); 8-bit tag in low mantissa.
        // Ss <= Bb invariant makes med3(Bb, p, Ss) the exact second-best.
        #pragma unroll
        for (int rt = 0; rt < 4; ++rt)
            #pragma unroll
            for (int rg = 0; rg < 4; ++rg) {
                int s = rt * 4 + rg;
                float p = __uint_as_float(
                    (__float_as_uint(acc[rt][rg]) & 0xFFFFFF00u) | kc8);
                Ss[s] = __builtin_amdgcn_fmed3f(Bb[s], p, Ss[s]);
                Bb[s] = fmaxf(Bb[s], p);
            }
        kc8 += 2;
    };

    short8 bA[8], bB[8];
    #pragma unroll
    for (int f = 0; f < 8; ++f) bA[f] = *(const short8*)(pb + f * 1024);

    for (int tt = 0; tt < 64; ++tt) {
        {   // even tile t = 2*tt: prefetch t+1 into bB, compute bA
            const int t = 2 * tt;
            const char* p = pb + (size_t)(t + 1) * 16384;
            #pragma unroll
            for (int f = 0; f < 8; ++f) bB[f] = *(const short8*)(p + f * 1024);
            tileStep(bA);
        }
        {   // odd tile t = 2*tt+1: prefetch t+1 into bA (clamp last), compute bB
            const int t = 2 * tt + 1;
            const size_t tn = (t < 127) ? (size_t)(t + 1) : (size_t)t;
            const char* p = pb + tn * 16384;
            #pragma unroll
            for (int f = 0; f < 8; ++f) bA[f] = *(const short8*)(p + f * 1024);
            tileStep(bB);
        }
    }

    // ---- epilogue: merge 16 m16-lanes per slot ----
    float mv1[16], mv2[16]; int mk1[16];
    #pragma unroll
    for (int s = 0; s < 16; ++s) {
        float v1 = Bb[s], v2 = Ss[s];
        int k1 = (int)(((__float_as_uint(v1) & 0xFFu) << 4) | (unsigned)m16);
        #pragma unroll
        for (int off = 1; off < 16; off <<= 1) {
            float ov1 = __shfl_xor(v1, off);
            float ov2 = __shfl_xor(v2, off);
            int   ok1 = __shfl_xor(k1, off);
            bool gt = ov1 > v1, eq = ov1 == v1;
            v2 = gt ? fmaxf(ov2, v1) : fmaxf(v2, ov1);
            v1 = gt ? ov1 : v1;
            k1 = gt ? ok1 : (eq ? min(k1, ok1) : k1);
        }
        mv1[s] = v1; mv2[s] = v2; mk1[s] = k1;
    }
    // cross-codeset merge via LDS: [256 rows][2 cs]
    float* Ev = (float*)smem;                // 2048 B
    float* Sv = (float*)(smem + 2048);
    int*   Kv = (int*)(smem + 4096);
    float* bsum = (float*)(smem + 6144);
    int*   sidx = (int*)(smem + 8192);       // [256] final code per row
    __syncthreads();
    if (tid == 0) *bsum = 0.f;
    if (m16 == 0) {
        #pragma unroll
        for (int s = 0; s < 16; ++s) {
            int rt = s >> 2, rg = s & 3;
            int row = rs * 64 + rt * 16 + quad * 4 + rg;   // C row = quad*4+reg
            Ev[row * 2 + cs] = mv1[s];
            Sv[row * 2 + cs] = mv2[s];
            Kv[row * 2 + cs] = mk1[s];
        }
    }
    __syncthreads();
    if (tid < 256) {
        float v1 = Ev[tid * 2], v2 = Sv[tid * 2];
        int   k1 = Kv[tid * 2];
        float ov1 = Ev[tid * 2 + 1], ov2 = Sv[tid * 2 + 1];
        int   ok1 = Kv[tid * 2 + 1];
        bool gt = ov1 > v1, eq = ov1 == v1;
        v2 = gt ? fmaxf(ov2, v1) : fmaxf(v2, ov1);
        v1 = gt ? ov1 : v1;
        k1 = gt ? ok1 : (eq ? min(k1, ok1) : k1);
        sidx[tid] = k1;
        atomicAdd(bsum, v1);
        if (v1 - v2 < TAU) {
            int pos = atomicAdd(rcnt, 1);
            if (pos < RCAP) rlist[pos] = n0 + tid;
        }
    }
    __syncthreads();
    if (tid == 0) atomicAdd(lossacc, *bsum);

    // ---- fused output write via LDS transpose: 4 chunks of 64 rows.
    // Stage: thread t loads row (t>>3) of chunk (code myk), dims (t&7)*16..+15
    // -> coalesced 128B runs per row. Write: 64 lanes = 64 consecutive l,
    // fixed d -> contiguous 256B stores.
    int myk[4];
    #pragma unroll
    for (int c = 0; c < 4; ++c) myk[c] = sidx[c * 64 + (tid >> 3)];
    float* tb = (float*)smem;                // [64][130] = 33280 B
    float* ob = out + (size_t)bI * Dc * Lc + l0;
    #pragma unroll 1
    for (int c = 0; c < 4; ++c) {
        __syncthreads();                     // prior chunk reads / sidx done
        {
            const float4* src = (const float4*)(cbn + (size_t)myk[c] * Dc + (tid & 7) * 16);
            float4 v0 = src[0], v1 = src[1], v2 = src[2], v3 = src[3];
            float* dst = tb + (tid >> 3) * 130 + (tid & 7) * 16;
            *(float4*)(dst + 0)  = v0;
            *(float4*)(dst + 4)  = v1;
            *(float4*)(dst + 8)  = v2;
            *(float4*)(dst + 12) = v3;
        }
        __syncthreads();
        {
            int l = tid & 63, d0 = tid >> 6;     // wave = fixed d, l 0..63
            #pragma unroll
            for (int dd = 0; dd < 16; ++dd) {
                int d = d0 * 16 + dd;
                ob[(size_t)d * Lc + c * 64 + l] = tb[l * 130 + d];
            }
        }
    }
}

// ---------------------------------------------------------------------------
// Exact fp32 re-argmax for flagged queries; rewrites the output row with the
// exact code. Ownership k = i*256 + tid (L2-friendly windows). Last block
// (device-scope done counter) writes the scalar loss.
// ---------------------------------------------------------------------------
__global__ __launch_bounds__(256)
void k_repair(const float* __restrict__ x, const float* __restrict__ invn,
              const float* __restrict__ cbn, float* __restrict__ out,
              const int* __restrict__ rcnt, const int* __restrict__ rlist,
              const float* __restrict__ lacc, int* __restrict__ done) {
    __shared__ float xs[128];
    __shared__ unsigned long long red[4];
    __shared__ int fk;
    int cnt = *rcnt; if (cnt > RCAP) cnt = RCAP;
    const int tid = threadIdx.x;
    for (int e = blockIdx.x; e < cnt; e += gridDim.x) {
        int n = rlist[e]; int b = n >> 12; int l = n & (Lc - 1);
        __syncthreads();
        if (tid < 128)
            xs[tid] = x[(size_t)b * Dc * Lc + (size_t)tid * Lc + l] * invn[n];
        __syncthreads();
        const float4* xv = (const float4*)xs;
        float best = -3.0e38f; int bk = 0;
        #pragma unroll 1
        for (int i = 0; i < 16; ++i) {
            int k = i * 256 + tid;                // ascending: '>' keeps min k
            const float4* cr = (const float4*)(cbn + (size_t)k * Dc);
            float s = 0.f;
            #pragma unroll
            for (int j = 0; j < 32; ++j) {
                float4 c = cr[j], xx = xv[j];
                s = fmaf(c.x, xx.x, s); s = fmaf(c.y, xx.y, s);
                s = fmaf(c.z, xx.z, s); s = fmaf(c.w, xx.w, s);
            }
            if (s > best) { best = s; bk = k; }
        }
        unsigned kb = __float_as_uint(best);
        kb = (kb & 0x80000000u) ? ~kb : (kb | 0x80000000u);
        unsigned long long pk =
            ((unsigned long long)kb << 32) | (unsigned)(0xFFFFFFFFu - (unsigned)bk);
        #pragma unroll
        for (int off = 32; off >= 1; off >>= 1) {
            unsigned long long o = __shfl_xor(pk, off);
            pk = (o > pk) ? o : pk;
        }
        if ((tid & 63) == 0) red[tid >> 6] = pk;
        __syncthreads();
        if (tid == 0) {
            unsigned long long m = red[0];
            for (int i = 1; i < 4; ++i) if (red[i] > m) m = red[i];
            fk = (int)(0xFFFFFFFFu - (unsigned)(m & 0xFFFFFFFFull));
        }
        __syncthreads();
        if (tid < 128)       // rewrite output row with exact code
            out[(size_t)b * Dc * Lc + (size_t)tid * Lc + l] = cbn[(size_t)fk * Dc + tid];
    }
    // ---- fused loss finalize: last block writes the scalar
    __syncthreads();
    if (tid == 0) {
        int old = atomicAdd(done, 1);
        if (old == (int)gridDim.x - 1)
            out[(size_t)Bc * Dc * Lc] = 2.0f - 2.0f * (*lacc) / (float)Nc;
    }
}

// ---------------------------------------------------------------------------
extern "C" void kernel_launch(void* const* d_in, const int* in_sizes, int n_in,
                              void* d_out, int out_size, void* d_ws, size_t ws_size,
                              hipStream_t stream) {
    const float* x   = (const float*)d_in[0];   // [16][128][4096] fp32
    const float* emb = (const float*)d_in[1];   // [4096][128] fp32
    float* out = (float*)d_out;

    char* ws = (char*)d_ws;
    float* cbn  = (float*)ws;                                  // 2 MB
    char*  blob = ws + (2u << 20);                             // 2 MB
    float* invn = (float*)(ws + (4u << 20));                   // 256 KB
    char*  b5   = ws + (4u << 20) + (512u << 10);
    float* lacc = (float*)b5;
    int*   rcnt = (int*)(b5 + 64);
    int*   done = (int*)(b5 + 128);
    int*   rlist= (int*)(b5 + 1024);                           // 128 KB

    k_prep  <<<Kc / 4,   256, 0, stream>>>(emb, cbn, blob, lacc, rcnt, done);
    k_argmax<<<Nc / 256, 512, 0, stream>>>(x, blob, cbn, invn, out, lacc, rcnt, rlist);
    k_repair<<<1024,     256, 0, stream>>>(x, invn, cbn, out, rcnt, rlist, lacc, done);
}